// Round 4
// baseline (546.189 us; speedup 1.0000x reference)
//
#include <hip/hip_runtime.h>
#include <hip/hip_bf16.h>

// GCN layer: out = ReLU( D^-1/2 (A+I) D^-1/2 X W + b ), N=8192, IN=OUT=256.
// fp32 I/O; bf16 internally for MFMA.
//   s = (rowsum(adj)+1)^-1/2 ; Z = X@W ;
//   out[i,n] = relu( s_i * sum_j adj[i,j]*s_j*Z[j,n] + s_i^2*Z[i,n] + b[n] )
// Primary path (needs 142MB ws): adjb = bf16(adj) pre-swizzled; barrier-free k_main.
//   adjb 16B-unit idx = (bm*128 + kt)*256 + kc*32 + mm   (row = bm*32+mm, k = kt*64+kc*8..+8)
//   Zsb  16B-unit idx = kt*2048 + kc*256 + n             (content = s_k*Z[k][n], k = kt*64+kc*8..+8)

typedef __attribute__((ext_vector_type(8))) short short8;
typedef __attribute__((ext_vector_type(4))) short short4v;
typedef __attribute__((ext_vector_type(4))) float floatx4;

#define GLDS16(g, l) __builtin_amdgcn_global_load_lds(\
    (const __attribute__((address_space(1))) void*)(g), \
    (__attribute__((address_space(3))) void*)(l), 16, 0, 0)

// fp32 -> bf16 round-to-nearest-even
__device__ __forceinline__ unsigned short f2b(float f) {
  unsigned int x = __builtin_bit_cast(unsigned int, f);
  unsigned int r = (x + 0x7fffu + ((x >> 16) & 1u)) >> 16;
  return (unsigned short)r;
}

// =================== PRIMARY PATH ===========================================

// ---- kernel 1: degree -> s ; adjb = swizzled bf16(adj) ---------------------
// 256 blocks x 256 threads; block bm: rows m0..m0+32. Per kt: read 8KB fp32
// coalesced, cvt, LDS shuffle (rotated slots to tame banks), write 4KB contig.
__global__ __launch_bounds__(256) void k_prep(
    const float* __restrict__ adj, float* __restrict__ s,
    unsigned short* __restrict__ adjb) {
  __shared__ __align__(16) unsigned short tile[256 * 8];  // 4KB: [kc][m'] units
  __shared__ float part[512];
  const int t = threadIdx.x;
  const int bm = blockIdx.x, m0 = bm * 32;
  const int mA = t >> 4, mB = 16 + (t >> 4);   // two fixed rows per thread
  const int c_ = t & 15;                        // float4 chunk within 64-k tile
  const float* src0 = adj + (size_t)(m0 + mA) * 8192 + c_ * 4;
  const float* src1 = adj + (size_t)(m0 + mB) * 8192 + c_ * 4;
  const int kc = c_ >> 1, h = c_ & 1;
  unsigned short* dst0 = tile + (size_t)(kc * 32 + ((mA + 4 * kc) & 31)) * 8 + h * 4;
  unsigned short* dst1 = tile + (size_t)(kc * 32 + ((mB + 4 * kc) & 31)) * 8 + h * 4;
  const int kcg = t >> 5, mmg = t & 31;         // copy-out: global unit g = t
  const unsigned short* osrc = tile + (size_t)(kcg * 32 + ((mmg + 4 * kcg) & 31)) * 8;
  unsigned short* obase = adjb + (size_t)bm * 128 * 2048 + t * 8;
  float rs0 = 0.f, rs1 = 0.f;
  float4 c0 = *(const float4*)(src0);
  float4 c1 = *(const float4*)(src1);
  for (int kt = 0; kt < 128; ++kt) {
    const int ktn = (kt + 1) & 127;             // wrap: last prefetch harmless
    float4 n0v = *(const float4*)(src0 + ktn * 64);
    float4 n1v = *(const float4*)(src1 + ktn * 64);
    rs0 += c0.x + c0.y + c0.z + c0.w;
    rs1 += c1.x + c1.y + c1.z + c1.w;
    short4v b0 = {(short)f2b(c0.x), (short)f2b(c0.y), (short)f2b(c0.z), (short)f2b(c0.w)};
    short4v b1 = {(short)f2b(c1.x), (short)f2b(c1.y), (short)f2b(c1.z), (short)f2b(c1.w)};
    *(short4v*)dst0 = b0;
    *(short4v*)dst1 = b1;
    __syncthreads();
    short8 v = *(const short8*)osrc;
    *(short8*)(obase + (size_t)kt * 2048) = v;
    __syncthreads();
    c0 = n0v; c1 = n1v;
  }
  part[t] = rs0; part[256 + t] = rs1;
  __syncthreads();
  if (t < 32) {
    float sum = 1.0f;
#pragma unroll
    for (int j = 0; j < 16; ++j) sum += part[t * 16 + j];
    s[m0 + t] = rsqrtf(sum);
  }
}

// ---- kernel 2: Z = X@W (VALU fp32) ; Zd = s^2 Z + b ; Zsb swizzled ---------
// 256 blocks x 256 threads (4 waves). Wave w: rows m0+w*8..+8; lane l: cols 4l..4l+4.
__global__ __launch_bounds__(256) void k_xw(
    const float* __restrict__ X, const float* __restrict__ W,
    const float* __restrict__ bias, const float* __restrict__ s,
    float* __restrict__ Zd, unsigned short* __restrict__ Zsb) {
  __shared__ unsigned short ldsT[256 * 36];   // [n][mm], stride 36 shorts (72B)
  const int t = threadIdx.x, l = t & 63, w = t >> 6;
  const int m0 = blockIdx.x * 32;
  const int r0 = w * 8;
  const int n0 = l * 4;
  const float* Xp = X + (size_t)(m0 + r0) * 256;
  float acc[8][4] = {};
#pragma unroll 2
  for (int k = 0; k < 256; k += 4) {
    float4 wv[4];
#pragma unroll
    for (int j = 0; j < 4; ++j) wv[j] = *(const float4*)(W + (size_t)(k + j) * 256 + n0);
#pragma unroll
    for (int r = 0; r < 8; ++r) {
      float4 xv = *(const float4*)(Xp + r * 256 + k);   // wave-uniform broadcast
      const float xs[4] = {xv.x, xv.y, xv.z, xv.w};
#pragma unroll
      for (int j = 0; j < 4; ++j) {
        acc[r][0] += xs[j] * wv[j].x;
        acc[r][1] += xs[j] * wv[j].y;
        acc[r][2] += xs[j] * wv[j].z;
        acc[r][3] += xs[j] * wv[j].w;
      }
    }
  }
  const float4 bv = *(const float4*)(bias + n0);
  const int kt = m0 >> 6, hh = (m0 >> 5) & 1;
#pragma unroll
  for (int r = 0; r < 8; ++r) {
    const int row = m0 + r0 + r;
    const float sr = s[row];
    float4 zd;
    zd.x = sr * sr * acc[r][0] + bv.x;
    zd.y = sr * sr * acc[r][1] + bv.y;
    zd.z = sr * sr * acc[r][2] + bv.z;
    zd.w = sr * sr * acc[r][3] + bv.w;
    *(float4*)(Zd + (size_t)row * 256 + n0) = zd;
#pragma unroll
    for (int n = 0; n < 4; ++n)
      ldsT[(size_t)(n0 + n) * 36 + (r0 + r)] = f2b(sr * acc[r][n]);
  }
  __syncthreads();
#pragma unroll
  for (int c = 0; c < 4; ++c) {
    const unsigned short* p = ldsT + (size_t)t * 36 + c * 8;
    short4v lo = *(const short4v*)(p);
    short4v hi = *(const short4v*)(p + 4);
    short8 vv;
    vv[0] = lo[0]; vv[1] = lo[1]; vv[2] = lo[2]; vv[3] = lo[3];
    vv[4] = hi[0]; vv[5] = hi[1]; vv[6] = hi[2]; vv[7] = hi[3];
    *(short8*)(Zsb + ((size_t)kt * 2048 + (hh * 4 + c) * 256 + t) * 8) = vv;
  }
}

// ---- kernel 3: out = relu(s_i*(adjb@Zsb) + Zd) — barrier-free K-loop -------
// 512 blocks x 128 threads (2 waves). block: rows (b>>1)*32, n-half (b&1)*128.
// Wave w: n-slice 64. Per-wave LDS: A 3x4KB + B 2x8KB. Manual vmcnt(16):
// B(kt) gets 1-iter slack (L2), A(kt) gets 2-iter slack (HBM). No __syncthreads.
__global__ __launch_bounds__(128) void k_main(
    const unsigned short* __restrict__ adjb, const unsigned short* __restrict__ Zsb,
    const float* __restrict__ s, const float* __restrict__ Zd,
    float* __restrict__ out) {
  __shared__ __align__(16) char lds[57344];   // 2 waves x (12KB A + 16KB B)
  const int t = threadIdx.x, l = t & 63, w = t >> 6;
  const int quad = l >> 4, nl = l & 15;
  const int bm = blockIdx.x >> 1;
  const int m0 = bm * 32;
  const int n0 = (blockIdx.x & 1) * 128 + w * 64;
  char* bufA = lds + w * 12288;
  char* bufB = lds + 24576 + w * 16384;
  const unsigned short* aB = adjb + (size_t)bm * 128 * 2048;
  floatx4 acc[2][4] = {};

  // prologue: A(0), B(0), A(1)
#pragma unroll
  for (int r = 0; r < 4; ++r)
    GLDS16(aB + (size_t)(r * 64 + l) * 8, bufA + (r * 64 + l) * 16);
#pragma unroll
  for (int r = 0; r < 8; ++r)
    GLDS16(Zsb + (size_t)(r * 256 + n0 + l) * 8, bufB + (r * 64 + l) * 16);
#pragma unroll
  for (int r = 0; r < 4; ++r)
    GLDS16(aB + (size_t)(256 + r * 64 + l) * 8, bufA + 4096 + (r * 64 + l) * 16);

  for (int kt = 0; kt < 128; ++kt) {
    const int ktb = kt < 127 ? kt + 1 : 127;   // B prefetch (1 ahead)
    const int kta = kt < 126 ? kt + 2 : 127;   // A prefetch (2 ahead)
    char* dstB = bufB + (ktb & 1) * 8192;
    char* dstA = bufA + (kta % 3) * 4096;
#pragma unroll
    for (int r = 0; r < 8; ++r)
      GLDS16(Zsb + (size_t)(ktb * 2048 + r * 256 + n0 + l) * 8, dstB + (r * 64 + l) * 16);
#pragma unroll
    for (int r = 0; r < 4; ++r)
      GLDS16(aB + (size_t)(kta * 256 + r * 64 + l) * 8, dstA + (r * 64 + l) * 16);
    asm volatile("s_waitcnt vmcnt(16)" ::: "memory");  // drains A(kt), B(kt); keeps 16 newest in flight
    const char* rA = bufA + (kt % 3) * 4096;
    const char* rB = bufB + (kt & 1) * 8192;
#pragma unroll
    for (int kk = 0; kk < 2; ++kk) {
      const int kc = kk * 4 + quad;
      short8 af[2], bf[4];
      af[0] = *(const short8*)(rA + (kc * 32 + nl) * 16);
      af[1] = *(const short8*)(rA + (kc * 32 + 16 + nl) * 16);
#pragma unroll
      for (int nf = 0; nf < 4; ++nf)
        bf[nf] = *(const short8*)(rB + (kc * 64 + nf * 16 + nl) * 16);
#pragma unroll
      for (int mi = 0; mi < 2; ++mi)
#pragma unroll
        for (int nf = 0; nf < 4; ++nf)
          acc[mi][nf] = __builtin_amdgcn_mfma_f32_16x16x32_bf16(af[mi], bf[nf], acc[mi][nf], 0, 0, 0);
    }
  }

#pragma unroll
  for (int mi = 0; mi < 2; ++mi)
#pragma unroll
    for (int nf = 0; nf < 4; ++nf)
#pragma unroll
      for (int r = 0; r < 4; ++r) {
        const int row = m0 + mi * 16 + quad * 4 + r;
        const int col = n0 + nf * 16 + nl;
        float v = s[row] * acc[mi][nf][r] + Zd[row * 256 + col];
        out[row * 256 + col] = v > 0.f ? v : 0.f;
      }
}

// =================== FALLBACK (verbatim R3, passed @528us) ==================
__global__ __launch_bounds__(256) void fb_prep(
    const float* __restrict__ adj, const float* __restrict__ W,
    const float* __restrict__ X, float* __restrict__ s,
    unsigned short* __restrict__ WT, unsigned short* __restrict__ Xb) {
  __shared__ float part[4];
  const int b = blockIdx.x, t = threadIdx.x;
  if (b < 8192) {
    const float4* row = (const float4*)(adj + (size_t)b * 8192);
    float sum = 0.f;
#pragma unroll
    for (int q = 0; q < 8; ++q) {
      float4 v = row[t + q * 256];
      sum += v.x + v.y + v.z + v.w;
    }
#pragma unroll
    for (int o = 32; o > 0; o >>= 1) sum += __shfl_down(sum, o, 64);
    if ((t & 63) == 0) part[t >> 6] = sum;
    __syncthreads();
    if (t == 0) s[b] = rsqrtf(part[0] + part[1] + part[2] + part[3] + 1.0f);
  } else if (b < 8256) {
    const int wb = b - 8192;
#pragma unroll
    for (int q = 0; q < 4; ++q) {
      int i = wb * 1024 + q * 256 + t;
      WT[i] = f2b(W[(i & 255) * 256 + (i >> 8)]);
    }
  } else {
    const int xb = b - 8256;
#pragma unroll
    for (int q = 0; q < 8; ++q) {
      int i = xb * 2048 + q * 256 + t;
      Xb[i] = f2b(X[i]);
    }
  }
}

__global__ __launch_bounds__(256) void fb_xw(
    const unsigned short* __restrict__ Xb, const unsigned short* __restrict__ WT,
    const float* __restrict__ bias, const float* __restrict__ s,
    float* __restrict__ Zd, unsigned short* __restrict__ Zsb) {
  __shared__ __align__(16) unsigned short ldsX[64 * 256];
  __shared__ __align__(16) unsigned short ldsW[64 * 256];
  __shared__ __align__(16) unsigned short ldsT[64 * 72];
  const int t = threadIdx.x, l = t & 63, w = t >> 6;
  const int quad = l >> 4, nl = l & 15;
  const int m0 = blockIdx.x * 64, n0 = blockIdx.y * 64;
#pragma unroll
  for (int r = 0; r < 8; ++r) {
    int sl = r * 256 + t;
    int kc = sl >> 6, mm = sl & 63;
    GLDS16(Xb + (m0 + mm) * 256 + kc * 8, (char*)ldsX + sl * 16);
    GLDS16(WT + (n0 + mm) * 256 + kc * 8, (char*)ldsW + sl * 16);
  }
  __syncthreads();
  const int wm = w & 1, wn = w >> 1;
  floatx4 acc[2][2] = {};
#pragma unroll
  for (int kk = 0; kk < 8; ++kk) {
    int kc = kk * 4 + quad;
    short8 af[2], bf[2];
#pragma unroll
    for (int i = 0; i < 2; ++i) {
      af[i] = *(const short8*)&ldsX[(kc * 64 + wm * 32 + i * 16 + nl) * 8];
      bf[i] = *(const short8*)&ldsW[(kc * 64 + wn * 32 + i * 16 + nl) * 8];
    }
#pragma unroll
    for (int mi = 0; mi < 2; ++mi)
#pragma unroll
      for (int ni = 0; ni < 2; ++ni)
        acc[mi][ni] = __builtin_amdgcn_mfma_f32_16x16x32_bf16(af[mi], bf[ni], acc[mi][ni], 0, 0, 0);
  }
#pragma unroll
  for (int mi = 0; mi < 2; ++mi)
#pragma unroll
    for (int ni = 0; ni < 2; ++ni)
#pragma unroll
      for (int r = 0; r < 4; ++r) {
        int row = m0 + wm * 32 + mi * 16 + quad * 4 + r;
        int col = n0 + wn * 32 + ni * 16 + nl;
        float v = acc[mi][ni][r];
        float sr = s[row];
        Zd[row * 256 + col] = sr * sr * v + bias[col];
        ldsT[(col - n0) * 72 + (row - m0)] = f2b(sr * v);
      }
  __syncthreads();
#pragma unroll
  for (int hq = 0; hq < 2; ++hq) {
    int c = hq * 256 + t;
    int kc = c >> 6, nn = c & 63;
    short8 val = *(const short8*)&ldsT[nn * 72 + kc * 8];
    *(short8*)(Zsb + (size_t)blockIdx.x * 16384 + kc * 2048 + (n0 + nn) * 8) = val;
  }
}

__global__ __launch_bounds__(512) void fb_main(
    const float* __restrict__ adj, const unsigned short* __restrict__ Zsb,
    const float* __restrict__ s, const float* __restrict__ Zd,
    float* __restrict__ out) {
  __shared__ __align__(16) char ldsA[2][8 * 544];
  __shared__ __align__(16) unsigned short ldsB[2][64 * 256];
  const int t = threadIdx.x, l = t & 63, w = t >> 6;
  const int quad = l >> 4, nl = l & 15;
  const int m0 = blockIdx.x * 32;
  const int aM = t >> 4, aC = t & 15;
  const float* aSrc = adj + (size_t)(m0 + aM) * 8192 + aC * 4;
  const int aOff = (aC >> 1) * 544 + aM * 16 + (aC & 1) * 8;
  floatx4 acc[2][2] = {};
  float4 av = *(const float4*)(aSrc);
#pragma unroll
  for (int r = 0; r < 4; ++r) {
    int sl = r * 512 + t;
    GLDS16(Zsb + (size_t)sl * 8, (char*)ldsB[0] + sl * 16);
  }
  {
    short4v ab = {(short)f2b(av.x), (short)f2b(av.y), (short)f2b(av.z), (short)f2b(av.w)};
    *(short4v*)(ldsA[0] + aOff) = ab;
  }
  __syncthreads();
  for (int kt = 0; kt < 128; ++kt) {
    const int cur = kt & 1, nxt = cur ^ 1;
    const int ktn = (kt < 127) ? kt + 1 : 127;
    av = *(const float4*)(aSrc + (size_t)ktn * 64);
#pragma unroll
    for (int r = 0; r < 4; ++r) {
      int sl = r * 512 + t;
      GLDS16(Zsb + (size_t)(ktn * 2048 + sl) * 8, (char*)ldsB[nxt] + sl * 16);
    }
#pragma unroll
    for (int kk = 0; kk < 2; ++kk) {
      int kc = kk * 4 + quad;
      short8 af[2], bf[2];
      af[0] = *(const short8*)(ldsA[cur] + kc * 544 + nl * 16);
      af[1] = *(const short8*)(ldsA[cur] + kc * 544 + (16 + nl) * 16);
      bf[0] = *(const short8*)&ldsB[cur][(kc * 256 + w * 32 + nl) * 8];
      bf[1] = *(const short8*)&ldsB[cur][(kc * 256 + w * 32 + 16 + nl) * 8];
      acc[0][0] = __builtin_amdgcn_mfma_f32_16x16x32_bf16(af[0], bf[0], acc[0][0], 0, 0, 0);
      acc[0][1] = __builtin_amdgcn_mfma_f32_16x16x32_bf16(af[0], bf[1], acc[0][1], 0, 0, 0);
      acc[1][0] = __builtin_amdgcn_mfma_f32_16x16x32_bf16(af[1], bf[0], acc[1][0], 0, 0, 0);
      acc[1][1] = __builtin_amdgcn_mfma_f32_16x16x32_bf16(af[1], bf[1], acc[1][1], 0, 0, 0);
    }
    {
      short4v ab = {(short)f2b(av.x), (short)f2b(av.y), (short)f2b(av.z), (short)f2b(av.w)};
      *(short4v*)(ldsA[nxt] + aOff) = ab;
    }
    __syncthreads();
  }
#pragma unroll
  for (int mi = 0; mi < 2; ++mi)
#pragma unroll
    for (int ni = 0; ni < 2; ++ni)
#pragma unroll
      for (int r = 0; r < 4; ++r) {
        int row = m0 + mi * 16 + quad * 4 + r;
        int col = w * 32 + ni * 16 + nl;
        float v = s[row] * acc[mi][ni][r] + Zd[row * 256 + col];
        out[row * 256 + col] = v > 0.f ? v : 0.f;
      }
}

// ============================================================================
extern "C" void kernel_launch(void* const* d_in, const int* in_sizes, int n_in,
                              void* d_out, int out_size, void* d_ws, size_t ws_size,
                              hipStream_t stream) {
  const float* X    = (const float*)d_in[0];   // [8192][256]
  const float* adj  = (const float*)d_in[1];   // [8192][8192]
  const float* W    = (const float*)d_in[2];   // [256][256] ([in][out])
  const float* bias = (const float*)d_in[3];   // [256]
  float* out = (float*)d_out;                  // [8192][256]
  char* ws = (char*)d_ws;

  const size_t need = (size_t)142 * 1024 * 1024;
  if (ws_size >= need) {
    float* s             = (float*)(ws);                         // 32 KB
    unsigned short* Zsb  = (unsigned short*)(ws + (1 << 20));    // 4 MB
    float* Zd            = (float*)(ws + (5 << 20));             // 8 MB
    unsigned short* adjb = (unsigned short*)(ws + ((size_t)13 << 20)); // 128 MB
    hipLaunchKernelGGL(k_prep, dim3(256), dim3(256), 0, stream, adj, s, adjb);
    hipLaunchKernelGGL(k_xw, dim3(256), dim3(256), 0, stream, X, W, bias, s, Zd, Zsb);
    hipLaunchKernelGGL(k_main, dim3(512), dim3(128), 0, stream, adjb, Zsb, s, Zd, out);
  } else {
    float* s            = (float*)(ws);
    unsigned short* WT  = (unsigned short*)(ws + 32768);
    unsigned short* Xb  = (unsigned short*)(ws + 262144);
    float* Zd           = (float*)(ws + (8 << 20));
    unsigned short* Zsb = (unsigned short*)(ws + (16 << 20));
    hipLaunchKernelGGL(fb_prep, dim3(9280), dim3(256), 0, stream, adj, W, X, s, WT, Xb);
    hipLaunchKernelGGL(fb_xw, dim3(128, 4), dim3(256), 0, stream, Xb, WT, bias, s, Zd, Zsb);
    hipLaunchKernelGGL(fb_main, dim3(256), dim3(512), 0, stream, adj, Zsb, s, Zd, out);
  }
}

// Round 5
// 526.511 us; speedup vs baseline: 1.0374x; 1.0374x over previous
//
#include <hip/hip_runtime.h>
#include <hip/hip_bf16.h>

// GCN layer: out = ReLU( D^-1/2 (A+I) D^-1/2 X W + b ), N=8192, IN=OUT=256.
// fp32 I/O; bf16 internally for MFMA.
//   deg = rowsum(adj); s_i = rsqrt(deg_i+1); Z = X@W;
//   out[i,n] = relu( s_i * sum_j adj[i,j]*s_j*Z[j,n] + s_i^2*Z[i,n] + b[n] )
// adjb 16B-unit idx = (bm64*128 + ktg)*512 + kc*64 + mm   (row = bm64*64+mm, k = ktg*64+kc*8..+8)
// Zsb  16B-unit idx = ktg*2048 + kc*256 + n               (content = s_k*Z[k][n])

typedef __attribute__((ext_vector_type(8))) short short8;
typedef __attribute__((ext_vector_type(4))) float floatx4;

#define GLDS16(g, l) __builtin_amdgcn_global_load_lds(\
    (const __attribute__((address_space(1))) void*)(g), \
    (__attribute__((address_space(3))) void*)(l), 16, 0, 0)

// fp32 -> bf16 round-to-nearest-even
__device__ __forceinline__ unsigned short f2b(float f) {
  unsigned int x = __builtin_bit_cast(unsigned int, f);
  unsigned int r = (x + 0x7fffu + ((x >> 16) & 1u)) >> 16;
  return (unsigned short)r;
}

// ---- kernel 1: degree partial sums + adjb = swizzled bf16(adj) -------------
// 1024 blocks x 256 thr; block = (row-group bg: 32 rows) x (K-quarter kq: 2048).
// Lane owns (row = m0 + t&31, kc = t>>5): reads 32B/iter, stores one 16B unit.
// No LDS in the loop, no barriers -> deep pipelining. Rowsum reduced at end.
__global__ __launch_bounds__(256) void k_prep(
    const float* __restrict__ adj, float* __restrict__ degree,
    unsigned short* __restrict__ adjb) {
  __shared__ float red[256];
  const int t = threadIdx.x;
  const int bg = blockIdx.x >> 2, kq = blockIdx.x & 3;
  const int m0 = bg * 32;
  const int row = m0 + (t & 31);
  const int kc = t >> 5;                       // 0..7
  const float* src = adj + (size_t)row * 8192 + kq * 2048 + kc * 8;
  unsigned short* dst = adjb +
      ((((size_t)(row >> 6)) * 128 + kq * 32) * 512 + kc * 64 + (row & 63)) * 8;
  float rs = 0.f;
#pragma unroll 4
  for (int kt = 0; kt < 32; ++kt) {
    float4 a = *(const float4*)(src + kt * 64);
    float4 b = *(const float4*)(src + kt * 64 + 4);
    rs += a.x + a.y + a.z + a.w + b.x + b.y + b.z + b.w;
    short8 u;
    u[0] = (short)f2b(a.x); u[1] = (short)f2b(a.y);
    u[2] = (short)f2b(a.z); u[3] = (short)f2b(a.w);
    u[4] = (short)f2b(b.x); u[5] = (short)f2b(b.y);
    u[6] = (short)f2b(b.z); u[7] = (short)f2b(b.w);
    *(short8*)(dst + (size_t)kt * 512 * 8) = u;
  }
  red[t] = rs;
  __syncthreads();
  if (t < 32) {
    float sum = red[t] + red[t + 32] + red[t + 64] + red[t + 96] +
                red[t + 128] + red[t + 160] + red[t + 192] + red[t + 224];
    atomicAdd(degree + m0 + t, sum);
  }
}

// ---- kernel 2: Z = X@W (VALU fp32) ; Zd = s^2 Z + b ; Zsb swizzled ---------
// 256 blocks x 256 thr (4 waves). Wave w: rows m0+w*8..+8; lane l: cols 4l..4l+4.
__global__ __launch_bounds__(256) void k_xw(
    const float* __restrict__ X, const float* __restrict__ W,
    const float* __restrict__ bias, const float* __restrict__ degree,
    float* __restrict__ Zd, unsigned short* __restrict__ Zsb) {
  __shared__ unsigned short ldsT[256 * 36];   // [n][mm], stride 36 shorts (72B)
  const int t = threadIdx.x, l = t & 63, w = t >> 6;
  const int m0 = blockIdx.x * 32;
  const int r0 = w * 8;
  const int n0 = l * 4;
  const float* Xp = X + (size_t)(m0 + r0) * 256;
  float acc[8][4] = {};
#pragma unroll 2
  for (int k = 0; k < 256; k += 4) {
    float4 wv[4];
#pragma unroll
    for (int j = 0; j < 4; ++j) wv[j] = *(const float4*)(W + (size_t)(k + j) * 256 + n0);
#pragma unroll
    for (int r = 0; r < 8; ++r) {
      float4 xv = *(const float4*)(Xp + r * 256 + k);   // wave-uniform broadcast
      const float xs[4] = {xv.x, xv.y, xv.z, xv.w};
#pragma unroll
      for (int j = 0; j < 4; ++j) {
        acc[r][0] += xs[j] * wv[j].x;
        acc[r][1] += xs[j] * wv[j].y;
        acc[r][2] += xs[j] * wv[j].z;
        acc[r][3] += xs[j] * wv[j].w;
      }
    }
  }
  const float4 bv = *(const float4*)(bias + n0);
  const int kt = m0 >> 6, hh = (m0 >> 5) & 1;
#pragma unroll
  for (int r = 0; r < 8; ++r) {
    const int row = m0 + r0 + r;
    const float sr = rsqrtf(degree[row] + 1.0f);
    float4 zd;
    zd.x = sr * sr * acc[r][0] + bv.x;
    zd.y = sr * sr * acc[r][1] + bv.y;
    zd.z = sr * sr * acc[r][2] + bv.z;
    zd.w = sr * sr * acc[r][3] + bv.w;
    *(float4*)(Zd + (size_t)row * 256 + n0) = zd;
#pragma unroll
    for (int n = 0; n < 4; ++n)
      ldsT[(size_t)(n0 + n) * 36 + (r0 + r)] = f2b(sr * acc[r][n]);
  }
  __syncthreads();
#pragma unroll
  for (int c = 0; c < 4; ++c) {
    const unsigned short* p = ldsT + (size_t)t * 36 + c * 8;
    short8 vv;
#pragma unroll
    for (int j = 0; j < 8; ++j) vv[j] = p[j];
    *(short8*)(Zsb + ((size_t)kt * 2048 + (hh * 4 + c) * 256 + t) * 8) = vv;
  }
}

// ---- kernel 3: P[sk] = adjb @ Zsb (partial over K-half) --------------------
// 512 blocks x 512 thr (8 waves). b: bm64 = b>>2, sk = (b>>1)&1, nh = b&1.
// BM=64, BN=128, BK=64. LDS dbuf 2x(A 8KB + B 16KB) = 48KB -> 2 blocks/CU,
// 16 waves/CU. All staging via lane-contiguous global_load_lds width=16.
__global__ __launch_bounds__(512) void k_main(
    const unsigned short* __restrict__ adjb, const unsigned short* __restrict__ Zsb,
    float* __restrict__ P0, float* __restrict__ P1) {
  __shared__ __align__(16) char lds[2][24576];   // per stage: A @0 (8KB), B @8192 (16KB)
  const int t = threadIdx.x, l = t & 63, w = t >> 6;
  const int quad = l >> 4, nl = l & 15;
  const int bm = blockIdx.x >> 2, sk = (blockIdx.x >> 1) & 1, nh = blockIdx.x & 1;
  const int wm = w & 1, wn = w >> 1;             // 2x4 wave grid, 32x32 per wave
  const unsigned short* aBase = adjb + ((size_t)bm * 128 + sk * 64) * 512 * 8;
  const int sl0 = t, sl1 = 512 + t;              // B slots (1024 units)
  const size_t bU0 = (size_t)(sl0 >> 7) * 256 + nh * 128 + (sl0 & 127);
  const size_t bU1 = (size_t)(sl1 >> 7) * 256 + nh * 128 + (sl1 & 127);
  floatx4 acc[2][2] = {};

  // prologue: tile 0
  GLDS16(aBase + (size_t)t * 8, lds[0] + t * 16);
  GLDS16(Zsb + ((size_t)(sk * 64) * 2048 + bU0) * 8, lds[0] + 8192 + sl0 * 16);
  GLDS16(Zsb + ((size_t)(sk * 64) * 2048 + bU1) * 8, lds[0] + 8192 + sl1 * 16);
  __syncthreads();

  for (int kt = 0; kt < 64; ++kt) {
    const int cur = kt & 1, nxt = cur ^ 1;
    const int ktn = kt < 63 ? kt + 1 : 63;       // last prefetch redundant, in-bounds
    // stage tile kt+1 (in flight during compute of kt)
    GLDS16(aBase + ((size_t)ktn * 512 + t) * 8, lds[nxt] + t * 16);
    GLDS16(Zsb + ((size_t)(sk * 64 + ktn) * 2048 + bU0) * 8, lds[nxt] + 8192 + sl0 * 16);
    GLDS16(Zsb + ((size_t)(sk * 64 + ktn) * 2048 + bU1) * 8, lds[nxt] + 8192 + sl1 * 16);
    // compute tile kt
    const char* rA = lds[cur];
    const char* rB = lds[cur] + 8192;
#pragma unroll
    for (int kk = 0; kk < 2; ++kk) {
      const int kc = kk * 4 + quad;
      short8 af[2], bf[2];
      af[0] = *(const short8*)(rA + (kc * 64 + wm * 32 + nl) * 16);
      af[1] = *(const short8*)(rA + (kc * 64 + wm * 32 + 16 + nl) * 16);
      bf[0] = *(const short8*)(rB + (kc * 128 + wn * 32 + nl) * 16);
      bf[1] = *(const short8*)(rB + (kc * 128 + wn * 32 + 16 + nl) * 16);
      acc[0][0] = __builtin_amdgcn_mfma_f32_16x16x32_bf16(af[0], bf[0], acc[0][0], 0, 0, 0);
      acc[0][1] = __builtin_amdgcn_mfma_f32_16x16x32_bf16(af[0], bf[1], acc[0][1], 0, 0, 0);
      acc[1][0] = __builtin_amdgcn_mfma_f32_16x16x32_bf16(af[1], bf[0], acc[1][0], 0, 0, 0);
      acc[1][1] = __builtin_amdgcn_mfma_f32_16x16x32_bf16(af[1], bf[1], acc[1][1], 0, 0, 0);
    }
    __syncthreads();   // drains tile kt+1's DMA; co-resident block overlaps the stall
  }

  float* P = sk ? P1 : P0;
#pragma unroll
  for (int mi = 0; mi < 2; ++mi)
#pragma unroll
    for (int ni = 0; ni < 2; ++ni)
#pragma unroll
      for (int r = 0; r < 4; ++r) {
        const int row = bm * 64 + wm * 32 + mi * 16 + quad * 4 + r;
        const int col = nh * 128 + wn * 32 + ni * 16 + nl;
        P[(size_t)row * 256 + col] = acc[mi][ni][r];
      }
}

// ---- kernel 4: out = relu( s_i*(P0+P1) + Zd ) ------------------------------
__global__ __launch_bounds__(256) void k_fin(
    const float* __restrict__ P0, const float* __restrict__ P1,
    const float* __restrict__ Zd, const float* __restrict__ degree,
    float* __restrict__ out) {
  const int i = blockIdx.x * 256 + threadIdx.x;     // float4 index
  const int row = i >> 6;
  const float sr = rsqrtf(degree[row] + 1.0f);
  const float4 p0 = *(const float4*)(P0 + (size_t)i * 4);
  const float4 p1 = *(const float4*)(P1 + (size_t)i * 4);
  const float4 zd = *(const float4*)(Zd + (size_t)i * 4);
  float4 v;
  v.x = sr * (p0.x + p1.x) + zd.x;
  v.y = sr * (p0.y + p1.y) + zd.y;
  v.z = sr * (p0.z + p1.z) + zd.z;
  v.w = sr * (p0.w + p1.w) + zd.w;
  v.x = v.x > 0.f ? v.x : 0.f;
  v.y = v.y > 0.f ? v.y : 0.f;
  v.z = v.z > 0.f ? v.z : 0.f;
  v.w = v.w > 0.f ? v.w : 0.f;
  *(float4*)(out + (size_t)i * 4) = v;
}

// ============================================================================
extern "C" void kernel_launch(void* const* d_in, const int* in_sizes, int n_in,
                              void* d_out, int out_size, void* d_ws, size_t ws_size,
                              hipStream_t stream) {
  const float* X    = (const float*)d_in[0];   // [8192][256]
  const float* adj  = (const float*)d_in[1];   // [8192][8192]
  const float* W    = (const float*)d_in[2];   // [256][256] ([in][out])
  const float* bias = (const float*)d_in[3];   // [256]
  float* out = (float*)d_out;                  // [8192][256]
  char* ws = (char*)d_ws;

  float* degree        = (float*)(ws);                              // 32 KB
  float* Zd            = (float*)(ws + (1 << 20));                  // 8 MB
  unsigned short* Zsb  = (unsigned short*)(ws + (9 << 20));         // 4 MB
  float* P0            = (float*)(ws + (13 << 20));                 // 8 MB
  float* P1            = (float*)(ws + (21 << 20));                 // 8 MB
  unsigned short* adjb = (unsigned short*)(ws + ((size_t)29 << 20)); // 128 MB (tot 157 MB)

  hipMemsetAsync(degree, 0, 8192 * sizeof(float), stream);
  hipLaunchKernelGGL(k_prep, dim3(1024), dim3(256), 0, stream, adj, degree, adjb);
  hipLaunchKernelGGL(k_xw, dim3(256), dim3(256), 0, stream, X, W, bias, degree, Zd, Zsb);
  hipLaunchKernelGGL(k_main, dim3(512), dim3(512), 0, stream, adjb, Zsb, P0, P1);
  hipLaunchKernelGGL(k_fin, dim3(2048), dim3(256), 0, stream, P0, P1, Zd, degree, out);
}

// Round 7
// 509.054 us; speedup vs baseline: 1.0729x; 1.0343x over previous
//
#include <hip/hip_runtime.h>
#include <hip/hip_bf16.h>

// GCN layer: out = ReLU( D^-1/2 (A+I) D^-1/2 X W + b ), N=8192, IN=OUT=256.
// fp32 I/O; bf16 internally for MFMA.
//   deg = rowsum(adj); s_i = rsqrt(deg_i+1); Z = X@W;
//   out[i,n] = relu( s_i * sum_j adj[i,j]*s_j*Z[j,n] + s_i^2*Z[i,n] + b[n] )
// No adjb round-trip: k_main reads fp32 adj once, converts in-register.
// Zsb (bf16 s_k*Z[k][n]) 16B-unit idx = ktg*2048 + kc*256 + n
//   (ktg = k/64, kc = (k/8)&7; each BK=32 tile i = contiguous 1024-unit span
//    starting at unit sk*65536 + i*1024 — local quad 0..3 = kc within tile)

typedef __attribute__((ext_vector_type(8))) short short8;
typedef __attribute__((ext_vector_type(4))) float floatx4;

#define GLDS16(g, l) __builtin_amdgcn_global_load_lds(\
    (const __attribute__((address_space(1))) void*)(g), \
    (__attribute__((address_space(3))) void*)(l), 16, 0, 0)

// fp32 -> bf16 round-to-nearest-even
__device__ __forceinline__ unsigned short f2b(float f) {
  unsigned int x = __builtin_bit_cast(unsigned int, f);
  unsigned int r = (x + 0x7fffu + ((x >> 16) & 1u)) >> 16;
  return (unsigned short)r;
}

// ---- kernel 1: degree = rowsum(adj) ----------------------------------------
// 1024 blocks x 256 thr (4/CU, 16 waves/CU). Row-subgroup = 32 lanes, 512B
// contiguous per row per iter. No LDS, no atomics, no barriers.
__global__ __launch_bounds__(256) void k_deg(
    const float* __restrict__ adj, float* __restrict__ degree) {
  const int t = threadIdx.x;
  const int row = blockIdx.x * 8 + (t >> 5);
  const int c = t & 31;
  const float* src = adj + (size_t)row * 8192 + c * 4;
  float rs = 0.f;
#pragma unroll 8
  for (int it = 0; it < 64; ++it) {
    float4 v = *(const float4*)(src + it * 128);
    rs += v.x + v.y + v.z + v.w;
  }
#pragma unroll
  for (int o = 16; o > 0; o >>= 1) rs += __shfl_down(rs, o, 32);
  if (c == 0) degree[row] = rs;
}

// ---- kernel 2: Z = X@W (VALU fp32) ; Zd = s^2 Z + b ; Zsb swizzled ---------
// 256 blocks x 256 thr (4 waves). Wave w: rows m0+w*8..+8; lane l: cols 4l..4l+4.
__global__ __launch_bounds__(256) void k_xw(
    const float* __restrict__ X, const float* __restrict__ W,
    const float* __restrict__ bias, const float* __restrict__ degree,
    float* __restrict__ Zd, unsigned short* __restrict__ Zsb) {
  __shared__ unsigned short ldsT[256 * 36];   // [n][mm], stride 36 shorts (72B)
  const int t = threadIdx.x, l = t & 63, w = t >> 6;
  const int m0 = blockIdx.x * 32;
  const int r0 = w * 8;
  const int n0 = l * 4;
  const float* Xp = X + (size_t)(m0 + r0) * 256;
  float acc[8][4] = {};
#pragma unroll 2
  for (int k = 0; k < 256; k += 4) {
    float4 wv[4];
#pragma unroll
    for (int j = 0; j < 4; ++j) wv[j] = *(const float4*)(W + (size_t)(k + j) * 256 + n0);
#pragma unroll
    for (int r = 0; r < 8; ++r) {
      float4 xv = *(const float4*)(Xp + r * 256 + k);   // wave-uniform broadcast
      const float xs[4] = {xv.x, xv.y, xv.z, xv.w};
#pragma unroll
      for (int j = 0; j < 4; ++j) {
        acc[r][0] += xs[j] * wv[j].x;
        acc[r][1] += xs[j] * wv[j].y;
        acc[r][2] += xs[j] * wv[j].z;
        acc[r][3] += xs[j] * wv[j].w;
      }
    }
  }
  const float4 bv = *(const float4*)(bias + n0);
  const int kt = m0 >> 6, hh = (m0 >> 5) & 1;
#pragma unroll
  for (int r = 0; r < 8; ++r) {
    const int row = m0 + r0 + r;
    const float sr = rsqrtf(degree[row] + 1.0f);
    float4 zd;
    zd.x = sr * sr * acc[r][0] + bv.x;
    zd.y = sr * sr * acc[r][1] + bv.y;
    zd.z = sr * sr * acc[r][2] + bv.z;
    zd.w = sr * sr * acc[r][3] + bv.w;
    *(float4*)(Zd + (size_t)row * 256 + n0) = zd;
#pragma unroll
    for (int n = 0; n < 4; ++n)
      ldsT[(size_t)(n0 + n) * 36 + (r0 + r)] = f2b(sr * acc[r][n]);
  }
  __syncthreads();
#pragma unroll
  for (int c = 0; c < 4; ++c) {
    const int kcv = hh * 4 + c;                 // kc of this 8-row group
    const unsigned short* p = ldsT + (size_t)t * 36 + c * 8;
    short8 vv;
#pragma unroll
    for (int j = 0; j < 8; ++j) vv[j] = p[j];
    *(short8*)(Zsb + ((size_t)kt * 2048 + kcv * 256 + t) * 8) = vv;
  }
}

// ---- kernel 3: P[sk] = adj(fp32,cvt) @ Zsb, split-K=4 ----------------------
// 512 blocks x 512 thr (exactly 2/CU, 16 waves/CU). b: bm = b>>2, sk = b&3.
// BM=64, BN=256, BK=32. Stage: A 4.2KB (cvt in-reg) + B 16KB (2 GLDS/thread,
// contiguous span). Dbuf, one barrier/iter; A/B prefetch issued at loop top.
__global__ __launch_bounds__(512) void k_main(
    const float* __restrict__ adj, const unsigned short* __restrict__ Zsb,
    float* __restrict__ P) {
  // per stage: A = 4*1040 = 4160 (pad to 4224, 16-al), B = 16384 -> 20608
  __shared__ __align__(16) char lds[2][20608];
  const int t = threadIdx.x, l = t & 63, w = t >> 6;
  const int quad = l >> 4, nl = l & 15;
  const int bm = blockIdx.x >> 2, sk = blockIdx.x & 3;
  const int m0 = bm * 64;
  const int wm = w & 1, wn = w >> 1;           // 2x4 wave grid, 32x64 per wave
  const int aRow = t >> 3, aCol = t & 7;
  const float* aSrc = adj + (size_t)(m0 + aRow) * 8192 + sk * 2048 + aCol * 4;
  const int aOff = (aCol >> 1) * 1040 + aRow * 16 + (aCol & 1) * 8;
  const unsigned short* bBase = Zsb + (size_t)sk * 65536 * 8;
  floatx4 acc[2][4] = {};

  // prologue: tile 0 staged, A(1) in flight
  float4 avP = *(const float4*)(aSrc);
#pragma unroll
  for (int q = 0; q < 2; ++q) {
    const int sl = q * 512 + t;
    GLDS16(bBase + (size_t)sl * 8, lds[0] + 4224 + sl * 16);
  }
  {
    unsigned short u0 = f2b(avP.x), u1 = f2b(avP.y), u2 = f2b(avP.z), u3 = f2b(avP.w);
    unsigned long long pk = (unsigned long long)u0 | ((unsigned long long)u1 << 16)
                          | ((unsigned long long)u2 << 32) | ((unsigned long long)u3 << 48);
    *(unsigned long long*)(lds[0] + aOff) = pk;
  }
  avP = *(const float4*)(aSrc + 32);
  __syncthreads();

  for (int i = 0; i < 64; ++i) {
    const int cur = i & 1, nxt = cur ^ 1;
    const int ib = i < 63 ? i + 1 : 63;        // B tile to stage (clamped, redundant ok)
    const int ia = i < 62 ? i + 2 : 63;        // A tile to fetch
    // issue B(i+1) DMA + A(i+2) load early: both in flight across compute
#pragma unroll
    for (int q = 0; q < 2; ++q) {
      const int sl = q * 512 + t;
      GLDS16(bBase + (size_t)(ib * 1024 + sl) * 8, lds[nxt] + 4224 + sl * 16);
    }
    float4 avN = *(const float4*)(aSrc + ia * 32);
    // compute tile i
    const char* rA = lds[cur];
    const char* rB = lds[cur] + 4224;
    short8 af[2], bf[4];
    af[0] = *(const short8*)(rA + quad * 1040 + (wm * 32 + nl) * 16);
    af[1] = *(const short8*)(rA + quad * 1040 + (wm * 32 + 16 + nl) * 16);
#pragma unroll
    for (int nf = 0; nf < 4; ++nf) {
      const int col = wn * 64 + nf * 16 + nl;
      bf[nf] = *(const short8*)(rB + ((size_t)quad * 256 + col) * 16);
    }
#pragma unroll
    for (int mi = 0; mi < 2; ++mi)
#pragma unroll
      for (int nf = 0; nf < 4; ++nf)
        acc[mi][nf] = __builtin_amdgcn_mfma_f32_16x16x32_bf16(af[mi], bf[nf], acc[mi][nf], 0, 0, 0);
    // stage A(i+1) from avP into nxt
    {
      unsigned short u0 = f2b(avP.x), u1 = f2b(avP.y), u2 = f2b(avP.z), u3 = f2b(avP.w);
      unsigned long long pk = (unsigned long long)u0 | ((unsigned long long)u1 << 16)
                            | ((unsigned long long)u2 << 32) | ((unsigned long long)u3 << 48);
      *(unsigned long long*)(lds[nxt] + aOff) = pk;
    }
    avP = avN;
    __syncthreads();
  }

  float* Pk = P + (size_t)sk * 8192 * 256;
#pragma unroll
  for (int mi = 0; mi < 2; ++mi)
#pragma unroll
    for (int nf = 0; nf < 4; ++nf)
#pragma unroll
      for (int r = 0; r < 4; ++r) {
        const int row = m0 + wm * 32 + mi * 16 + quad * 4 + r;
        const int col = wn * 64 + nf * 16 + nl;
        Pk[(size_t)row * 256 + col] = acc[mi][nf][r];
      }
}

// ---- kernel 4: out = relu( s_i*(P0+P1+P2+P3) + Zd ) ------------------------
__global__ __launch_bounds__(256) void k_fin(
    const float* __restrict__ P, const float* __restrict__ Zd,
    const float* __restrict__ degree, float* __restrict__ out) {
  const int i = blockIdx.x * 256 + threadIdx.x;     // float4 index
  const int row = i >> 6;
  const float sr = rsqrtf(degree[row] + 1.0f);
  const size_t stride = (size_t)8192 * 256;
  float4 p0 = *(const float4*)(P + (size_t)i * 4);
  float4 p1 = *(const float4*)(P + stride + (size_t)i * 4);
  float4 p2 = *(const float4*)(P + 2 * stride + (size_t)i * 4);
  float4 p3 = *(const float4*)(P + 3 * stride + (size_t)i * 4);
  const float4 zd = *(const float4*)(Zd + (size_t)i * 4);
  float4 v;
  v.x = sr * ((p0.x + p1.x) + (p2.x + p3.x)) + zd.x;
  v.y = sr * ((p0.y + p1.y) + (p2.y + p3.y)) + zd.y;
  v.z = sr * ((p0.z + p1.z) + (p2.z + p3.z)) + zd.z;
  v.w = sr * ((p0.w + p1.w) + (p2.w + p3.w)) + zd.w;
  v.x = v.x > 0.f ? v.x : 0.f;
  v.y = v.y > 0.f ? v.y : 0.f;
  v.z = v.z > 0.f ? v.z : 0.f;
  v.w = v.w > 0.f ? v.w : 0.f;
  *(float4*)(out + (size_t)i * 4) = v;
}

// ============================================================================
extern "C" void kernel_launch(void* const* d_in, const int* in_sizes, int n_in,
                              void* d_out, int out_size, void* d_ws, size_t ws_size,
                              hipStream_t stream) {
  const float* X    = (const float*)d_in[0];   // [8192][256]
  const float* adj  = (const float*)d_in[1];   // [8192][8192]
  const float* W    = (const float*)d_in[2];   // [256][256] ([in][out])
  const float* bias = (const float*)d_in[3];   // [256]
  float* out = (float*)d_out;                  // [8192][256]
  char* ws = (char*)d_ws;

  float* degree       = (float*)(ws);                      // 32 KB
  float* Zd           = (float*)(ws + (1 << 20));          // 8 MB
  unsigned short* Zsb = (unsigned short*)(ws + (9 << 20)); // 4 MB
  float* P            = (float*)(ws + (13 << 20));         // 32 MB (4 x 8 MB)  total 45 MB

  hipLaunchKernelGGL(k_deg, dim3(1024), dim3(256), 0, stream, adj, degree);
  hipLaunchKernelGGL(k_xw, dim3(256), dim3(256), 0, stream, X, W, bias, degree, Zd, Zsb);
  hipLaunchKernelGGL(k_main, dim3(512), dim3(512), 0, stream, adj, Zsb, P);
  hipLaunchKernelGGL(k_fin, dim3(2048), dim3(256), 0, stream, P, Zd, degree, out);
}